// Round 4
// baseline (176.767 us; speedup 1.0000x reference)
//
#include <hip/hip_runtime.h>
#include <math.h>

#define DEVINL __device__ __forceinline__

typedef __attribute__((ext_vector_type(8))) short bf16x8;
typedef __attribute__((ext_vector_type(4))) float f32x4;

DEVINL float sigm(float x) { return __builtin_amdgcn_rcpf(1.0f + __expf(-x)); }
DEVINL float tanh_(float x) { return fmaf(2.0f, __builtin_amdgcn_rcpf(1.0f + __expf(-2.0f * x)), -1.0f); }

DEVINL unsigned short f2bf(float f) {
    union { float f; unsigned u; } v; v.f = f;
    unsigned r = v.u + 0x7FFFu + ((v.u >> 16) & 1u);   // RNE
    return (unsigned short)(r >> 16);
}

DEVINL bf16x8 pack8(const float* p) {
    bf16x8 r;
#pragma unroll
    for (int e = 0; e < 8; ++e) r[e] = (short)f2bf(p[e]);
    return r;
}

DEVINL unsigned cvt_pk_bf16(float lo, float hi) {
    unsigned r;
    asm("v_cvt_pk_bf16_f32 %0, %1, %2" : "=v"(r) : "v"(lo), "v"(hi));
    return r;
}

// lane xor-8 within each 16-lane row, as a VALU op (DPP row_ror:8)
DEVINL float dpp_xor8(float x) {
    int r = __builtin_amdgcn_update_dpp(0, __builtin_bit_cast(int, x),
                                        0x128 /*ROW_ROR:8*/, 0xF, 0xF, false);
    return __builtin_bit_cast(float, r);
}

// ---------------------------------------------------------------------------
// Fused kernel, grid 768:
//   blocks [0,512)   : edge LSTM, 4 seqs each (person i = b>>1, s = 4*(b&1)+n)
//   blocks [512,768) : node LSTM, 1 batch row each
// Placement: 3 blocks/CU -> 2 independent edge chains per CU (latency hiding).
//
// Edge, per wave w (u-group [16w,16w+16)), per step j:
//   acc[q] = mfma(A1,B1, mfma(A0,B0, base_q))   (q = gate type; cols 0-3 = seqs)
//   DPP row_ror:8 ships regs {2,3} from lanes c<4 to lanes 8-11
//     -> 2 cell updates per lane on 32 lanes
//   + Wih*scene_j, activations, cvt_pk -> bf16 h, conflict-free LDS write
// h tile: [4 seqs][64 u] bf16, chunk-rotated (u>>3 + 2n)&7, double-buffered.
// ---------------------------------------------------------------------------
__global__ __launch_bounds__(256, 1) void fused_node_edge_k(
    const float* __restrict__ scene,      // [256][8][2]
    const float* __restrict__ eWih, const float* __restrict__ eWhh,
    const float* __restrict__ ebih, const float* __restrict__ ebhh,
    const float* __restrict__ nWih, const float* __restrict__ nWhh,
    const float* __restrict__ nbih, const float* __restrict__ nbhh,
    float* __restrict__ dist_hist,        // [2048][64]
    float* __restrict__ lstm_out)         // [256][8][64]
{
    __shared__ __align__(16) float lds_sc[256 * 8];   // 8 KB (edge: 4 timesteps)
    __shared__ __align__(16) unsigned hbuf[2][128];   // 2 x 512 B (edge h tiles)
    __shared__ __align__(16) float lds_h[64];         // (node)
    __shared__ float lds_g[256];                      // (node)

    const int t = threadIdx.x;

    if (blockIdx.x < 512) {
        // ================= EDGE =================
        const int b   = blockIdx.x;
        const int i   = b >> 1;
        const int sh  = b & 1;
        const int w   = t >> 6;
        const int l   = t & 63;
        const int lg  = l >> 4;          // 0..3
        const int col = l & 15;          // MFMA col; seqs live in cols 0..3
        const int n   = col & 3;         // seq within block
        const int hi  = (col >> 3) & 1;  // post-DPP: which reg-pair this lane owns
        const bool act = ((col & 7) < 4);

        // stage scene[:, 4sh..4sh+4, :] (thread t loads person t, 32B)
        {
            const float4* src = reinterpret_cast<const float4*>(scene + t * 16 + 8 * sh);
            float4* dst = reinterpret_cast<float4*>(&lds_sc[t * 8]);
            dst[0] = src[0]; dst[1] = src[1];
            reinterpret_cast<unsigned*>(&hbuf[0][0])[t] = 0u;   // zero both h tiles
        }

        // A fragments: row = 64q + 16w + col, k = 32*kt + 8*lg + e
        bf16x8 afrag[4][2];
#pragma unroll
        for (int q = 0; q < 4; ++q) {
            const int arow = 64 * q + 16 * w + col;
#pragma unroll
            for (int kt = 0; kt < 2; ++kt) {
                float tmp[8];
                float4 v0 = *reinterpret_cast<const float4*>(&eWhh[arow * 64 + kt * 32 + lg * 8]);
                float4 v1 = *reinterpret_cast<const float4*>(&eWhh[arow * 64 + kt * 32 + lg * 8 + 4]);
                tmp[0]=v0.x; tmp[1]=v0.y; tmp[2]=v0.z; tmp[3]=v0.w;
                tmp[4]=v1.x; tmp[5]=v1.y; tmp[6]=v1.z; tmp[7]=v1.w;
                afrag[q][kt] = pack8(tmp);
            }
        }

        // C-in base: bias - Wih*scene_i (pre-DPP slots: row u = 16w+4lg+r, col n)
        const float sxi = scene[i * 16 + (4 * sh + n) * 2 + 0];
        const float syi = scene[i * 16 + (4 * sh + n) * 2 + 1];
        f32x4 base[4];
#pragma unroll
        for (int q = 0; q < 4; ++q)
#pragma unroll
            for (int r = 0; r < 4; ++r) {
                const int g = 64 * q + 16 * w + 4 * lg + r;
                base[q][r] = ebih[g] + ebhh[g] - eWih[2*g] * sxi - eWih[2*g + 1] * syi;
            }

        // worker-side Wih for this lane's 2 updates: u = 16w + 4lg + 2hi + sl
        float wxw[4][2], wyw[4][2];
#pragma unroll
        for (int q = 0; q < 4; ++q)
#pragma unroll
            for (int sl = 0; sl < 2; ++sl) {
                const int g = 64 * q + 16 * w + 4 * lg + 2 * hi + sl;
                wxw[q][sl] = eWih[2*g];
                wyw[q][sl] = eWih[2*g + 1];
            }

        // h-tile byte addrs: elem(n,u) at 128n + 16*(((u>>3)+2n)&7) + (2u&15)
        const int rdA = 128 * n + 16 * ((lg + 2 * n) & 7);            // kt=0
        const int rdB = 128 * n + 16 * ((lg + 4 + 2 * n) & 7);        // kt=1
        const int wrb = 128 * n + 16 * ((2 * w + (lg >> 1) + 2 * n) & 7)
                      + 8 * (lg & 1) + 4 * hi;

        float c0 = 0.f, c1 = 0.f, h0 = 0.f, h1 = 0.f;
        int cur = 0;
        __syncthreads();

#pragma unroll 1
        for (int j = 0; j < 256; ++j) {
            const char* hb = reinterpret_cast<const char*>(&hbuf[cur][0]);
            bf16x8 b0 = *reinterpret_cast<const bf16x8*>(hb + rdA);
            bf16x8 b1 = *reinterpret_cast<const bf16x8*>(hb + rdB);
            float2 sc = *reinterpret_cast<const float2*>(&lds_sc[j * 8 + 2 * n]);

            f32x4 acc[4];
#pragma unroll
            for (int q = 0; q < 4; ++q) {
                acc[q] = __builtin_amdgcn_mfma_f32_16x16x32_bf16(afrag[q][0], b0, base[q], 0, 0, 0);
                acc[q] = __builtin_amdgcn_mfma_f32_16x16x32_bf16(afrag[q][1], b1, acc[q], 0, 0, 0);
            }

            // rebalance: lanes hi=0 keep regs {0,1}; lanes hi=1 get regs {2,3} via DPP
            float p0[4], p1[4];
#pragma unroll
            for (int q = 0; q < 4; ++q) {
                const float d2 = dpp_xor8(acc[q][2]);
                const float d3 = dpp_xor8(acc[q][3]);
                p0[q] = hi ? d2 : acc[q][0];
                p1[q] = hi ? d3 : acc[q][1];
            }
#pragma unroll
            for (int q = 0; q < 4; ++q) {
                p0[q] = fmaf(wyw[q][0], sc.y, fmaf(wxw[q][0], sc.x, p0[q]));
                p1[q] = fmaf(wyw[q][1], sc.y, fmaf(wxw[q][1], sc.x, p1[q]));
            }

            {
                const float gi = sigm(p0[0]), gf = sigm(p0[1]);
                const float gg = tanh_(p0[2]), go = sigm(p0[3]);
                c0 = fmaf(gf, c0, gi * gg);
                h0 = go * tanh_(c0);
            }
            {
                const float gi = sigm(p1[0]), gf = sigm(p1[1]);
                const float gg = tanh_(p1[2]), go = sigm(p1[3]);
                c1 = fmaf(gf, c1, gi * gg);
                h1 = go * tanh_(c1);
            }

            if (act) {
                char* hw = reinterpret_cast<char*>(&hbuf[cur ^ 1][0]);
                *reinterpret_cast<unsigned*>(hw + wrb) = cvt_pk_bf16(h0, h1);
            }
            __syncthreads();
            cur ^= 1;
        }

        if (act) {
            const int row = i * 8 + 4 * sh + n;
            const int u0  = 16 * w + 4 * lg + 2 * hi;
            *reinterpret_cast<float2*>(&dist_hist[row * 64 + u0]) = make_float2(h0, h1);
        }

    } else {
        // ================= NODE =================
        const int b = blockIdx.x - 512;
        float whh[64];
#pragma unroll
        for (int k = 0; k < 64; k += 4) {
            float4 v = *reinterpret_cast<const float4*>(&nWhh[t * 64 + k]);
            whh[k] = v.x; whh[k+1] = v.y; whh[k+2] = v.z; whh[k+3] = v.w;
        }
        const float wx = nWih[2*t], wy = nWih[2*t + 1];
        const float bias = nbih[t] + nbhh[t];
        float c = 0.0f;
        if (t < 64) lds_h[t] = 0.0f;
        __syncthreads();

#pragma unroll 1
        for (int step = 0; step < 8; ++step) {
            const float x0 = scene[b*16 + step*2 + 0];
            const float x1 = scene[b*16 + step*2 + 1];
            float acc = wx * x0 + wy * x1 + bias;
#pragma unroll
            for (int k = 0; k < 64; k += 4) {
                float4 h4 = *reinterpret_cast<const float4*>(&lds_h[k]);
                acc += whh[k]*h4.x + whh[k+1]*h4.y + whh[k+2]*h4.z + whh[k+3]*h4.w;
            }
            const float gv = ((t >> 6) == 2) ? tanh_(acc) : sigm(acc);
            lds_g[t] = gv;
            __syncthreads();
            if (t < 64) {
                const float gi = lds_g[t], gf = lds_g[64+t], gc = lds_g[128+t], go = lds_g[192+t];
                c = gf * c + gi * gc;
                const float h = go * tanh_(c);
                lds_h[t] = h;
                lstm_out[(b*8 + step)*64 + t] = h;
            }
            __syncthreads();
        }
    }
}

// ---------------------------------------------------------------------------
// seq LSTM. B=256, T=8, In=64, H=64.
// ---------------------------------------------------------------------------
__global__ __launch_bounds__(256) void seq_lstm_k(
    const float* __restrict__ dist_hist, const float* __restrict__ Wih,
    const float* __restrict__ Whh, const float* __restrict__ bih,
    const float* __restrict__ bhh, float* __restrict__ out)
{
    const int b = blockIdx.x;
    const int t = threadIdx.x;
    __shared__ __align__(16) float lds_h[64];
    __shared__ __align__(16) float lds_x[64];
    __shared__ float lds_g[256];

    float whh[64], wih[64];
#pragma unroll
    for (int k = 0; k < 64; k += 4) {
        float4 v = *reinterpret_cast<const float4*>(&Whh[t * 64 + k]);
        whh[k] = v.x; whh[k+1] = v.y; whh[k+2] = v.z; whh[k+3] = v.w;
        float4 u = *reinterpret_cast<const float4*>(&Wih[t * 64 + k]);
        wih[k] = u.x; wih[k+1] = u.y; wih[k+2] = u.z; wih[k+3] = u.w;
    }
    const float bias = bih[t] + bhh[t];
    float c = 0.0f;
    if (t < 64) lds_h[t] = 0.0f;
    __syncthreads();

#pragma unroll 1
    for (int step = 0; step < 8; ++step) {
        if (t < 64) lds_x[t] = dist_hist[(b*8 + step)*64 + t];
        __syncthreads();
        float acc = bias;
#pragma unroll
        for (int k = 0; k < 64; k += 4) {
            float4 h4 = *reinterpret_cast<const float4*>(&lds_h[k]);
            float4 x4 = *reinterpret_cast<const float4*>(&lds_x[k]);
            acc += whh[k]*h4.x + whh[k+1]*h4.y + whh[k+2]*h4.z + whh[k+3]*h4.w;
            acc += wih[k]*x4.x + wih[k+1]*x4.y + wih[k+2]*x4.z + wih[k+3]*x4.w;
        }
        const float gv = ((t >> 6) == 2) ? tanh_(acc) : sigm(acc);
        lds_g[t] = gv;
        __syncthreads();
        if (t < 64) {
            const float gi = lds_g[t], gf = lds_g[64+t], gc = lds_g[128+t], go = lds_g[192+t];
            c = gf * c + gi * gc;
            const float h = go * tanh_(c);
            lds_h[t] = h;
            out[(b*8 + step)*64 + t] = h;
        }
        __syncthreads();
    }
}

// ---------------------------------------------------------------------------
// decoder LSTM + pose head. In=128, H=32, T=8.
// ---------------------------------------------------------------------------
__global__ __launch_bounds__(128) void dec_lstm_k(
    const float* __restrict__ lstm_out, const float* __restrict__ full_dist,
    const float* __restrict__ scene, const float* __restrict__ Wih,
    const float* __restrict__ Whh, const float* __restrict__ bih,
    const float* __restrict__ bhh, const float* __restrict__ pose_W,
    const float* __restrict__ pose_b, float* __restrict__ out)
{
    const int b = blockIdx.x;
    const int t = threadIdx.x;
    __shared__ __align__(16) float lds_h[32];
    __shared__ __align__(16) float lds_x[128];
    __shared__ float lds_g[128];
    __shared__ float lds_dec[8][32];

    float wih[128];
#pragma unroll
    for (int k = 0; k < 128; k += 4) {
        float4 u = *reinterpret_cast<const float4*>(&Wih[t * 128 + k]);
        wih[k] = u.x; wih[k+1] = u.y; wih[k+2] = u.z; wih[k+3] = u.w;
    }
    float whh[32];
#pragma unroll
    for (int k = 0; k < 32; k += 4) {
        float4 v = *reinterpret_cast<const float4*>(&Whh[t * 32 + k]);
        whh[k] = v.x; whh[k+1] = v.y; whh[k+2] = v.z; whh[k+3] = v.w;
    }
    const float bias = bih[t] + bhh[t];
    float c = 0.0f;
    if (t < 32) lds_h[t] = 0.0f;
    __syncthreads();

#pragma unroll 1
    for (int step = 0; step < 8; ++step) {
        if (t < 64) lds_x[t] = lstm_out[(b*8 + step)*64 + t];
        else        lds_x[t] = full_dist[(b*8 + step)*64 + (t - 64)];
        __syncthreads();
        float acc = bias;
#pragma unroll
        for (int k = 0; k < 128; k += 4) {
            float4 x4 = *reinterpret_cast<const float4*>(&lds_x[k]);
            acc += wih[k]*x4.x + wih[k+1]*x4.y + wih[k+2]*x4.z + wih[k+3]*x4.w;
        }
#pragma unroll
        for (int k = 0; k < 32; k += 4) {
            float4 h4 = *reinterpret_cast<const float4*>(&lds_h[k]);
            acc += whh[k]*h4.x + whh[k+1]*h4.y + whh[k+2]*h4.z + whh[k+3]*h4.w;
        }
        const float gv = ((t >> 5) == 2) ? tanh_(acc) : sigm(acc);
        lds_g[t] = gv;
        __syncthreads();
        if (t < 32) {
            const float gi = lds_g[t], gf = lds_g[32+t], gc = lds_g[64+t], go = lds_g[96+t];
            c = gf * c + gi * gc;
            const float h = go * tanh_(c);
            lds_h[t] = h;
            lds_dec[step][t] = h;
        }
        __syncthreads();
    }

    // pose head: wave 0 -> d=0, wave 1 -> d=1; 64-lane partial + shuffle reduce
    {
        const int lane = t & 63;
        const int d = t >> 6;
        const float* dec_flat = &lds_dec[0][0];
        float part = 0.f;
#pragma unroll
        for (int k = 0; k < 4; ++k)
            part += dec_flat[lane + 64*k] * pose_W[d*256 + lane + 64*k];
#pragma unroll
        for (int off = 32; off; off >>= 1)
            part += __shfl_down(part, off, 64);
        if (lane == 0)
            out[b*2 + d] = part + scene[b*16 + 14 + d] + pose_b[d];
    }
}

// ---------------------------------------------------------------------------
extern "C" void kernel_launch(void* const* d_in, const int* in_sizes, int n_in,
                              void* d_out, int out_size, void* d_ws, size_t ws_size,
                              hipStream_t stream) {
    const float* scene    = (const float*)d_in[0];
    const float* node_Wih = (const float*)d_in[1];
    const float* node_Whh = (const float*)d_in[2];
    const float* node_bih = (const float*)d_in[3];
    const float* node_bhh = (const float*)d_in[4];
    const float* edge_Wih = (const float*)d_in[5];
    const float* edge_Whh = (const float*)d_in[6];
    const float* edge_bih = (const float*)d_in[7];
    const float* edge_bhh = (const float*)d_in[8];
    const float* seq_Wih  = (const float*)d_in[9];
    const float* seq_Whh  = (const float*)d_in[10];
    const float* seq_bih  = (const float*)d_in[11];
    const float* seq_bhh  = (const float*)d_in[12];
    const float* dec_Wih  = (const float*)d_in[13];
    const float* dec_Whh  = (const float*)d_in[14];
    const float* dec_bih  = (const float*)d_in[15];
    const float* dec_bhh  = (const float*)d_in[16];
    const float* pose_W   = (const float*)d_in[17];
    const float* pose_b   = (const float*)d_in[18];
    float* out = (float*)d_out;

    float* ws = (float*)d_ws;
    float* lstm_out  = ws;               // 256*8*64
    float* dist_hist = ws + 131072;      // 256*8*64
    float* full_dist = ws + 262144;      // 256*8*64

    fused_node_edge_k<<<768, 256, 0, stream>>>(scene,
        edge_Wih, edge_Whh, edge_bih, edge_bhh,
        node_Wih, node_Whh, node_bih, node_bhh,
        dist_hist, lstm_out);
    seq_lstm_k<<<256, 256, 0, stream>>>(dist_hist, seq_Wih, seq_Whh, seq_bih, seq_bhh, full_dist);
    dec_lstm_k<<<256, 128, 0, stream>>>(lstm_out, full_dist, scene, dec_Wih, dec_Whh,
                                        dec_bih, dec_bhh, pose_W, pose_b, out);
}

// Round 5
// 125.243 us; speedup vs baseline: 1.4114x; 1.4114x over previous
//
#include <hip/hip_runtime.h>
#include <math.h>

#define DEVINL __device__ __forceinline__

typedef __attribute__((ext_vector_type(8))) short bf16x8;
typedef __attribute__((ext_vector_type(4))) float f32x4;

DEVINL float sigm(float x) { return __builtin_amdgcn_rcpf(1.0f + __expf(-x)); }
DEVINL float tanh_(float x) { return fmaf(2.0f, __builtin_amdgcn_rcpf(1.0f + __expf(-2.0f * x)), -1.0f); }

DEVINL unsigned short f2bf(float f) {
    union { float f; unsigned u; } v; v.f = f;
    unsigned r = v.u + 0x7FFFu + ((v.u >> 16) & 1u);   // RNE
    return (unsigned short)(r >> 16);
}

DEVINL bf16x8 pack8(const float* p) {
    bf16x8 r;
#pragma unroll
    for (int e = 0; e < 8; ++e) r[e] = (short)f2bf(p[e]);
    return r;
}

DEVINL unsigned cvt_pk_bf16(float lo, float hi) {
    unsigned r;
    asm("v_cvt_pk_bf16_f32 %0, %1, %2" : "=v"(r) : "v"(lo), "v"(hi));
    return r;
}

// lane ror-8 within each 16-lane row, VALU pipe (DPP) — NOT the LDS pipe
DEVINL float dpp_ror8(float x) {
    int r = __builtin_amdgcn_update_dpp(0, __builtin_bit_cast(int, x),
                                        0x128 /*ROW_ROR:8*/, 0xF, 0xF, false);
    return __builtin_bit_cast(float, r);
}

// ---------------------------------------------------------------------------
// Fused kernel, grid 512:
//   blocks [0,256)   : edge LSTM, 8 seqs each (person i = blockIdx, s = 0..7)
//   blocks [256,512) : node LSTM, 1 batch row each
// Each CU hosts 1 edge + 1 node block; node finishes in ~5 us.
//
// Edge (R3 structure, DS-pipe decongested):
//   - wave w owns u-group [16w,16w+16), all 4 gates; 8 MFMA/step
//   - DPP ror:8 (VALU) rebalances cols 0-7's regs{2,3} onto lanes 8-15
//     -> 2 cell updates/lane on all 64 lanes, no ds_swizzle
//   - scene staged transposed [s][j][2] (+8-float row pad): 1 ds_read_b128
//     per 2 steps (j-loop unrolled x2)
//   - h tile: R3's proven XOR layout (idx = u ^ 8n), double-buffered 1KB
//   Per-step DS ops/wave: 2 read_b128 + 1 write_b32 + 0.5 read_b128.
// ---------------------------------------------------------------------------
__global__ __launch_bounds__(256, 1) void fused_node_edge_k(
    const float* __restrict__ scene,      // [256][8][2]
    const float* __restrict__ eWih, const float* __restrict__ eWhh,
    const float* __restrict__ ebih, const float* __restrict__ ebhh,
    const float* __restrict__ nWih, const float* __restrict__ nWhh,
    const float* __restrict__ nbih, const float* __restrict__ nbhh,
    float* __restrict__ dist_hist,        // [2048][64]
    float* __restrict__ lstm_out)         // [256][8][64]
{
    __shared__ __align__(16) float lds_sc[8][520];             // 16.6 KB (edge)
    __shared__ __align__(16) unsigned short hbuf[2][512];      // 2 x 1 KB (edge)
    __shared__ __align__(16) float lds_h[64];                  // (node)
    __shared__ float lds_g[256];                               // (node)

    const int t = threadIdx.x;

    if (blockIdx.x < 256) {
        // ================= EDGE =================
        const int i  = blockIdx.x;
        const int w  = t >> 6;           // wave -> u-group
        const int l  = t & 63;
        const int lg = l >> 4;           // 0..3 (k-group / reg-row-group)
        const int nc = l & 15;           // MFMA col
        const int n  = l & 7;            // seq (= timestep s)
        const int hi = (nc >> 3) & 1;    // post-DPP reg-pair owner

        // ---- stage scene transposed: lds_sc[s][2j+xy]; zero h buffers ----
        {
            const float4* src = reinterpret_cast<const float4*>(scene + t * 16);
            float4 v0 = src[0], v1 = src[1], v2 = src[2], v3 = src[3];
            *reinterpret_cast<float2*>(&lds_sc[0][2*t]) = make_float2(v0.x, v0.y);
            *reinterpret_cast<float2*>(&lds_sc[1][2*t]) = make_float2(v0.z, v0.w);
            *reinterpret_cast<float2*>(&lds_sc[2][2*t]) = make_float2(v1.x, v1.y);
            *reinterpret_cast<float2*>(&lds_sc[3][2*t]) = make_float2(v1.z, v1.w);
            *reinterpret_cast<float2*>(&lds_sc[4][2*t]) = make_float2(v2.x, v2.y);
            *reinterpret_cast<float2*>(&lds_sc[5][2*t]) = make_float2(v2.z, v2.w);
            *reinterpret_cast<float2*>(&lds_sc[6][2*t]) = make_float2(v3.x, v3.y);
            *reinterpret_cast<float2*>(&lds_sc[7][2*t]) = make_float2(v3.z, v3.w);
            unsigned* z = reinterpret_cast<unsigned*>(&hbuf[0][0]);
            z[t] = 0u; z[t + 256] = 0u;
        }

        // ---- A fragments: row = 64q + 16w + nc, k = 32*kt + 8*lg + e ----
        bf16x8 afrag[4][2];
#pragma unroll
        for (int q = 0; q < 4; ++q) {
            const int arow = 64 * q + 16 * w + nc;
#pragma unroll
            for (int kt = 0; kt < 2; ++kt) {
                float tmp[8];
                float4 v0 = *reinterpret_cast<const float4*>(&eWhh[arow * 64 + kt * 32 + lg * 8]);
                float4 v1 = *reinterpret_cast<const float4*>(&eWhh[arow * 64 + kt * 32 + lg * 8 + 4]);
                tmp[0]=v0.x; tmp[1]=v0.y; tmp[2]=v0.z; tmp[3]=v0.w;
                tmp[4]=v1.x; tmp[5]=v1.y; tmp[6]=v1.z; tmp[7]=v1.w;
                afrag[q][kt] = pack8(tmp);
            }
        }

        // ---- C-in base: bias - Wih*scene_i (pre-DPP slots; col nc -> seq nc&7)
        const float sxi = scene[i * 16 + (nc & 7) * 2 + 0];
        const float syi = scene[i * 16 + (nc & 7) * 2 + 1];
        f32x4 base[4];
#pragma unroll
        for (int q = 0; q < 4; ++q)
#pragma unroll
            for (int r = 0; r < 4; ++r) {
                const int g = 64 * q + 16 * w + 4 * lg + r;
                base[q][r] = ebih[g] + ebhh[g] - eWih[2*g] * sxi - eWih[2*g + 1] * syi;
            }

        // ---- worker-side Wih for this lane's 2 units: u = 16w+4lg+2hi+sl ----
        float wxw[4][2], wyw[4][2];
#pragma unroll
        for (int q = 0; q < 4; ++q)
#pragma unroll
            for (int sl = 0; sl < 2; ++sl) {
                const int g = 64 * q + 16 * w + 4 * lg + 2 * hi + sl;
                wxw[q][sl] = eWih[2*g];
                wyw[q][sl] = eWih[2*g + 1];
            }

        // ---- h-tile byte addrs (R3's proven XOR layout: idx = u ^ 8n) ----
        const int rdA = n * 128 + 2 * ((32 * (0 ^ (n >> 2))) + 8 * (lg ^ (n & 3)));
        const int rdB = n * 128 + 2 * ((32 * (1 ^ (n >> 2))) + 8 * (lg ^ (n & 3)));
        const int u0  = 16 * w + 4 * lg + 2 * hi;
        const int wrb = n * 128 + 2 * (u0 ^ (n << 3));

        const float* scrow = &lds_sc[n][0];
        float c0 = 0.f, c1 = 0.f, h0 = 0.f, h1 = 0.f;
        __syncthreads();

#define EDGE_STEP(RB, WB, SCX, SCY) do {                                          \
        const char* hb = reinterpret_cast<const char*>(&hbuf[RB][0]);             \
        bf16x8 b0 = *reinterpret_cast<const bf16x8*>(hb + rdA);                   \
        bf16x8 b1 = *reinterpret_cast<const bf16x8*>(hb + rdB);                   \
        f32x4 acc[4];                                                             \
        _Pragma("unroll")                                                         \
        for (int q = 0; q < 4; ++q) {                                             \
            acc[q] = __builtin_amdgcn_mfma_f32_16x16x32_bf16(afrag[q][0], b0, base[q], 0, 0, 0); \
            acc[q] = __builtin_amdgcn_mfma_f32_16x16x32_bf16(afrag[q][1], b1, acc[q], 0, 0, 0);  \
        }                                                                         \
        float p0[4], p1[4];                                                       \
        _Pragma("unroll")                                                         \
        for (int q = 0; q < 4; ++q) {                                             \
            const float d2 = dpp_ror8(acc[q][2]);                                 \
            const float d3 = dpp_ror8(acc[q][3]);                                 \
            p0[q] = hi ? d2 : acc[q][0];                                          \
            p1[q] = hi ? d3 : acc[q][1];                                          \
        }                                                                         \
        _Pragma("unroll")                                                         \
        for (int q = 0; q < 4; ++q) {                                             \
            p0[q] = fmaf(wyw[q][0], (SCY), fmaf(wxw[q][0], (SCX), p0[q]));        \
            p1[q] = fmaf(wyw[q][1], (SCY), fmaf(wxw[q][1], (SCX), p1[q]));        \
        }                                                                         \
        {                                                                         \
            const float gi = sigm(p0[0]), gf = sigm(p0[1]);                       \
            const float gg = tanh_(p0[2]), go = sigm(p0[3]);                      \
            c0 = fmaf(gf, c0, gi * gg);                                           \
            h0 = go * tanh_(c0);                                                  \
        }                                                                         \
        {                                                                         \
            const float gi = sigm(p1[0]), gf = sigm(p1[1]);                       \
            const float gg = tanh_(p1[2]), go = sigm(p1[3]);                      \
            c1 = fmaf(gf, c1, gi * gg);                                           \
            h1 = go * tanh_(c1);                                                  \
        }                                                                         \
        char* hw = reinterpret_cast<char*>(&hbuf[WB][0]);                         \
        *reinterpret_cast<unsigned*>(hw + wrb) = cvt_pk_bf16(h0, h1);             \
        __syncthreads();                                                          \
    } while (0)

#pragma unroll 1
        for (int j = 0; j < 256; j += 2) {
            float4 s4 = *reinterpret_cast<const float4*>(&scrow[2 * j]);
            EDGE_STEP(0, 1, s4.x, s4.y);
            EDGE_STEP(1, 0, s4.z, s4.w);
        }
#undef EDGE_STEP

        // final h (f32) -> dist_hist[(i*8+n)][u0..u0+1]
        *reinterpret_cast<float2*>(&dist_hist[(i * 8 + n) * 64 + u0]) = make_float2(h0, h1);

    } else {
        // ================= NODE =================
        const int b = blockIdx.x - 256;
        float whh[64];
#pragma unroll
        for (int k = 0; k < 64; k += 4) {
            float4 v = *reinterpret_cast<const float4*>(&nWhh[t * 64 + k]);
            whh[k] = v.x; whh[k+1] = v.y; whh[k+2] = v.z; whh[k+3] = v.w;
        }
        const float wx = nWih[2*t], wy = nWih[2*t + 1];
        const float bias = nbih[t] + nbhh[t];
        float c = 0.0f;
        if (t < 64) lds_h[t] = 0.0f;
        __syncthreads();

#pragma unroll 1
        for (int step = 0; step < 8; ++step) {
            const float x0 = scene[b*16 + step*2 + 0];
            const float x1 = scene[b*16 + step*2 + 1];
            float acc = wx * x0 + wy * x1 + bias;
#pragma unroll
            for (int k = 0; k < 64; k += 4) {
                float4 h4 = *reinterpret_cast<const float4*>(&lds_h[k]);
                acc += whh[k]*h4.x + whh[k+1]*h4.y + whh[k+2]*h4.z + whh[k+3]*h4.w;
            }
            const float gv = ((t >> 6) == 2) ? tanh_(acc) : sigm(acc);
            lds_g[t] = gv;
            __syncthreads();
            if (t < 64) {
                const float gi = lds_g[t], gf = lds_g[64+t], gc = lds_g[128+t], go = lds_g[192+t];
                c = gf * c + gi * gc;
                const float h = go * tanh_(c);
                lds_h[t] = h;
                lstm_out[(b*8 + step)*64 + t] = h;
            }
            __syncthreads();
        }
    }
}

// ---------------------------------------------------------------------------
// seq LSTM. B=256, T=8, In=64, H=64.
// ---------------------------------------------------------------------------
__global__ __launch_bounds__(256) void seq_lstm_k(
    const float* __restrict__ dist_hist, const float* __restrict__ Wih,
    const float* __restrict__ Whh, const float* __restrict__ bih,
    const float* __restrict__ bhh, float* __restrict__ out)
{
    const int b = blockIdx.x;
    const int t = threadIdx.x;
    __shared__ __align__(16) float lds_h[64];
    __shared__ __align__(16) float lds_x[64];
    __shared__ float lds_g[256];

    float whh[64], wih[64];
#pragma unroll
    for (int k = 0; k < 64; k += 4) {
        float4 v = *reinterpret_cast<const float4*>(&Whh[t * 64 + k]);
        whh[k] = v.x; whh[k+1] = v.y; whh[k+2] = v.z; whh[k+3] = v.w;
        float4 u = *reinterpret_cast<const float4*>(&Wih[t * 64 + k]);
        wih[k] = u.x; wih[k+1] = u.y; wih[k+2] = u.z; wih[k+3] = u.w;
    }
    const float bias = bih[t] + bhh[t];
    float c = 0.0f;
    if (t < 64) lds_h[t] = 0.0f;
    __syncthreads();

#pragma unroll 1
    for (int step = 0; step < 8; ++step) {
        if (t < 64) lds_x[t] = dist_hist[(b*8 + step)*64 + t];
        __syncthreads();
        float acc = bias;
#pragma unroll
        for (int k = 0; k < 64; k += 4) {
            float4 h4 = *reinterpret_cast<const float4*>(&lds_h[k]);
            float4 x4 = *reinterpret_cast<const float4*>(&lds_x[k]);
            acc += whh[k]*h4.x + whh[k+1]*h4.y + whh[k+2]*h4.z + whh[k+3]*h4.w;
            acc += wih[k]*x4.x + wih[k+1]*x4.y + wih[k+2]*x4.z + wih[k+3]*x4.w;
        }
        const float gv = ((t >> 6) == 2) ? tanh_(acc) : sigm(acc);
        lds_g[t] = gv;
        __syncthreads();
        if (t < 64) {
            const float gi = lds_g[t], gf = lds_g[64+t], gc = lds_g[128+t], go = lds_g[192+t];
            c = gf * c + gi * gc;
            const float h = go * tanh_(c);
            lds_h[t] = h;
            out[(b*8 + step)*64 + t] = h;
        }
        __syncthreads();
    }
}

// ---------------------------------------------------------------------------
// decoder LSTM + pose head. In=128, H=32, T=8.
// ---------------------------------------------------------------------------
__global__ __launch_bounds__(128) void dec_lstm_k(
    const float* __restrict__ lstm_out, const float* __restrict__ full_dist,
    const float* __restrict__ scene, const float* __restrict__ Wih,
    const float* __restrict__ Whh, const float* __restrict__ bih,
    const float* __restrict__ bhh, const float* __restrict__ pose_W,
    const float* __restrict__ pose_b, float* __restrict__ out)
{
    const int b = blockIdx.x;
    const int t = threadIdx.x;
    __shared__ __align__(16) float lds_h[32];
    __shared__ __align__(16) float lds_x[128];
    __shared__ float lds_g[128];
    __shared__ float lds_dec[8][32];

    float wih[128];
#pragma unroll
    for (int k = 0; k < 128; k += 4) {
        float4 u = *reinterpret_cast<const float4*>(&Wih[t * 128 + k]);
        wih[k] = u.x; wih[k+1] = u.y; wih[k+2] = u.z; wih[k+3] = u.w;
    }
    float whh[32];
#pragma unroll
    for (int k = 0; k < 32; k += 4) {
        float4 v = *reinterpret_cast<const float4*>(&Whh[t * 32 + k]);
        whh[k] = v.x; whh[k+1] = v.y; whh[k+2] = v.z; whh[k+3] = v.w;
    }
    const float bias = bih[t] + bhh[t];
    float c = 0.0f;
    if (t < 32) lds_h[t] = 0.0f;
    __syncthreads();

#pragma unroll 1
    for (int step = 0; step < 8; ++step) {
        if (t < 64) lds_x[t] = lstm_out[(b*8 + step)*64 + t];
        else        lds_x[t] = full_dist[(b*8 + step)*64 + (t - 64)];
        __syncthreads();
        float acc = bias;
#pragma unroll
        for (int k = 0; k < 128; k += 4) {
            float4 x4 = *reinterpret_cast<const float4*>(&lds_x[k]);
            acc += wih[k]*x4.x + wih[k+1]*x4.y + wih[k+2]*x4.z + wih[k+3]*x4.w;
        }
#pragma unroll
        for (int k = 0; k < 32; k += 4) {
            float4 h4 = *reinterpret_cast<const float4*>(&lds_h[k]);
            acc += whh[k]*h4.x + whh[k+1]*h4.y + whh[k+2]*h4.z + whh[k+3]*h4.w;
        }
        const float gv = ((t >> 5) == 2) ? tanh_(acc) : sigm(acc);
        lds_g[t] = gv;
        __syncthreads();
        if (t < 32) {
            const float gi = lds_g[t], gf = lds_g[32+t], gc = lds_g[64+t], go = lds_g[96+t];
            c = gf * c + gi * gc;
            const float h = go * tanh_(c);
            lds_h[t] = h;
            lds_dec[step][t] = h;
        }
        __syncthreads();
    }

    // pose head: wave 0 -> d=0, wave 1 -> d=1; 64-lane partial + shuffle reduce
    {
        const int lane = t & 63;
        const int d = t >> 6;
        const float* dec_flat = &lds_dec[0][0];
        float part = 0.f;
#pragma unroll
        for (int k = 0; k < 4; ++k)
            part += dec_flat[lane + 64*k] * pose_W[d*256 + lane + 64*k];
#pragma unroll
        for (int off = 32; off; off >>= 1)
            part += __shfl_down(part, off, 64);
        if (lane == 0)
            out[b*2 + d] = part + scene[b*16 + 14 + d] + pose_b[d];
    }
}

// ---------------------------------------------------------------------------
extern "C" void kernel_launch(void* const* d_in, const int* in_sizes, int n_in,
                              void* d_out, int out_size, void* d_ws, size_t ws_size,
                              hipStream_t stream) {
    const float* scene    = (const float*)d_in[0];
    const float* node_Wih = (const float*)d_in[1];
    const float* node_Whh = (const float*)d_in[2];
    const float* node_bih = (const float*)d_in[3];
    const float* node_bhh = (const float*)d_in[4];
    const float* edge_Wih = (const float*)d_in[5];
    const float* edge_Whh = (const float*)d_in[6];
    const float* edge_bih = (const float*)d_in[7];
    const float* edge_bhh = (const float*)d_in[8];
    const float* seq_Wih  = (const float*)d_in[9];
    const float* seq_Whh  = (const float*)d_in[10];
    const float* seq_bih  = (const float*)d_in[11];
    const float* seq_bhh  = (const float*)d_in[12];
    const float* dec_Wih  = (const float*)d_in[13];
    const float* dec_Whh  = (const float*)d_in[14];
    const float* dec_bih  = (const float*)d_in[15];
    const float* dec_bhh  = (const float*)d_in[16];
    const float* pose_W   = (const float*)d_in[17];
    const float* pose_b   = (const float*)d_in[18];
    float* out = (float*)d_out;

    float* ws = (float*)d_ws;
    float* lstm_out  = ws;               // 256*8*64
    float* dist_hist = ws + 131072;      // 256*8*64
    float* full_dist = ws + 262144;      // 256*8*64

    fused_node_edge_k<<<512, 256, 0, stream>>>(scene,
        edge_Wih, edge_Whh, edge_bih, edge_bhh,
        node_Wih, node_Whh, node_bih, node_bhh,
        dist_hist, lstm_out);
    seq_lstm_k<<<256, 256, 0, stream>>>(dist_hist, seq_Wih, seq_Whh, seq_bih, seq_bhh, full_dist);
    dec_lstm_k<<<256, 128, 0, stream>>>(lstm_out, full_dist, scene, dec_Wih, dec_Whh,
                                        dec_bih, dec_bhh, pose_W, pose_b, out);
}